// Round 2
// baseline (27236.633 us; speedup 1.0000x reference)
//
#include <hip/hip_runtime.h>
#include <math.h>

// ---------------------------------------------------------------------------
// DeepMonocularModel — full fp32 pipeline, correctness-first baseline (r2).
// All conv tensors flow in NHWC ( [b,y,x,c] ), which makes the conv GEMM
// epilogue layout == token layout for free.
// B=32 D=768 HF=WF=32 NTOK=1024 K=50 T=30 OUT_DIM=60 L=4 NH=8 HD=96 MLP=3072
// ---------------------------------------------------------------------------

#define NB   32
#define ND   768
#define NTOK 1024
#define NKH  8      // heads
#define NHD  96     // head dim
#define NL   4
#define NMLP 3072
#define NK   50
#define NT   30

__device__ __forceinline__ float gelu_f(float x) {
    return 0.5f * x * (1.0f + erff(x * 0.70710678118654752f));
}
__device__ __forceinline__ float softplus_f(float x) {
    return x > 0.f ? x + log1pf(expf(-x)) : log1pf(expf(x));
}

// ---------------------------------------------------------------------------
// Generic tiled GEMM: C[M,N] = act(A_view[M,K] @ B[K,N] + bias[N]) (+ res[M,N])
// AMODE: 0 = plain row-major A (lda=K)
//        1 = im2col of NHWC tensor, 3x3 conv pad=1 (out spatial == in spatial)
//        2 = im2col of NHWC tensor with 2x nearest upsample (out = 2*in)
// BT: 0 = B row-major (K,N);  1 = B is OIHW conv weights: Bw[n*K + ci*9 + r]
// ACT: 0 none, 1 gelu.  RES: add res[M,N] after activation.
// C always written as C[m*N+n]  (for conv: NHWC).
// ---------------------------------------------------------------------------
template<int AMODE, int BT, int ACT, int RES>
__global__ __launch_bounds__(256) void gemm_k(
    const float* __restrict__ A, const float* __restrict__ Bw,
    const float* __restrict__ bias, const float* __restrict__ res,
    float* __restrict__ C, int M, int N, int K,
    int Cin, int Hin, int Win, int hwShift, int wShift)
{
    __shared__ float As[16][68];
    __shared__ float Bs[16][68];
    const int tx = threadIdx.x, ty = threadIdx.y;
    const int tid = ty * 16 + tx;
    const int bm = blockIdx.y * 64, bn = blockIdx.x * 64;
    float acc[4][4] = {};

    for (int k0 = 0; k0 < K; k0 += 16) {
        // ---- A tile: 64 (m) x 16 (k) ----
#pragma unroll
        for (int i = 0; i < 4; i++) {
            int idx = i * 256 + tid;
            int ml = idx >> 4, kl = idx & 15;
            int m = bm + ml, k = k0 + kl;
            float v = 0.f;
            if (m < M && k < K) {
                if constexpr (AMODE == 0) {
                    v = A[(size_t)m * K + k];
                } else {
                    int b   = m >> hwShift;
                    int rem = m & ((1 << hwShift) - 1);
                    int y   = rem >> wShift;
                    int x   = rem & ((1 << wShift) - 1);
                    int ci  = k / 9;
                    int r   = k - ci * 9;
                    int yy  = y + r / 3 - 1;
                    int xx  = x + r % 3 - 1;
                    int Wo  = 1 << wShift;
                    int Ho  = 1 << (hwShift - wShift);
                    if (yy >= 0 && yy < Ho && xx >= 0 && xx < Wo) {
                        int iy = yy, ix = xx;
                        if constexpr (AMODE == 2) { iy = yy >> 1; ix = xx >> 1; }
                        // NHWC read
                        v = A[(((size_t)b * Hin + iy) * Win + ix) * Cin + ci];
                    }
                }
            }
            As[kl][ml] = v;
        }
        // ---- B tile: 16 (k) x 64 (n) ----
#pragma unroll
        for (int i = 0; i < 4; i++) {
            int idx = i * 256 + tid;
            int kl, nl;
            if constexpr (BT == 0) { nl = idx & 63; kl = idx >> 6; }
            else                   { kl = idx & 15; nl = idx >> 4; }
            int k = k0 + kl, n = bn + nl;
            float v = 0.f;
            if (k < K && n < N)
                v = (BT == 0) ? Bw[(size_t)k * N + n] : Bw[(size_t)n * K + k];
            Bs[kl][nl] = v;
        }
        __syncthreads();
#pragma unroll
        for (int kk = 0; kk < 16; kk++) {
            const float4 av = *reinterpret_cast<const float4*>(&As[kk][ty * 4]);
            const float4 bv = *reinterpret_cast<const float4*>(&Bs[kk][tx * 4]);
            const float a4[4] = {av.x, av.y, av.z, av.w};
            const float b4[4] = {bv.x, bv.y, bv.z, bv.w};
#pragma unroll
            for (int i = 0; i < 4; i++)
#pragma unroll
                for (int j = 0; j < 4; j++)
                    acc[i][j] = fmaf(a4[i], b4[j], acc[i][j]);
        }
        __syncthreads();
    }
    // ---- epilogue ----
#pragma unroll
    for (int i = 0; i < 4; i++) {
        int m = bm + ty * 4 + i;
        if (m >= M) continue;
#pragma unroll
        for (int j = 0; j < 4; j++) {
            int n = bn + tx * 4 + j;
            if (n >= N) continue;
            float v = acc[i][j] + bias[n];
            if constexpr (ACT == 1) v = gelu_f(v);
            if constexpr (RES == 1) v += res[(size_t)m * N + n];
            C[(size_t)m * N + n] = v;
        }
    }
}

// tokens[b,n,d] = feats_nhwc[b,n,d] + pos[n,d]   (vectorized float4)
__global__ void tokens_k(const float* __restrict__ f,
                         const float* __restrict__ pos,
                         float* __restrict__ tok)
{
    size_t i = ((size_t)blockIdx.x * 256 + threadIdx.x) * 4;
    if (i >= (size_t)NB * NTOK * ND) return;
    const float4 a = *reinterpret_cast<const float4*>(f + i);
    const float4 p = *reinterpret_cast<const float4*>(pos + (i & (NTOK * ND - 1)));
    float4 r;
    r.x = a.x + p.x; r.y = a.y + p.y; r.z = a.z + p.z; r.w = a.w + p.w;
    *reinterpret_cast<float4*>(tok + i) = r;
}

// depth[b,y,x] (128x128) = softplus(sum_ci w3[ci]*d2_nhwc[b,y/2,x/2,ci] + b3)
__global__ void depth_k(const float* __restrict__ d2,
                        const float* __restrict__ w3, const float* __restrict__ b3,
                        float* __restrict__ out)
{
    int idx = blockIdx.x * 256 + threadIdx.x;
    if (idx >= NB * 128 * 128) return;
    int b = idx >> 14;
    int rem = idx & 16383;
    int y = rem >> 7, x = rem & 127;
    const float* base = d2 + (((size_t)b * 64 + (y >> 1)) * 64 + (x >> 1)) * 32;
    float acc = b3[0];
#pragma unroll
    for (int ci = 0; ci < 32; ci++) acc = fmaf(base[ci], w3[ci], acc);
    out[idx] = softplus_f(acc);
}

// LayerNorm over 768
__global__ void ln_k(const float* __restrict__ x, const float* __restrict__ g,
                     const float* __restrict__ bb, float* __restrict__ y)
{
    int r = blockIdx.x, t = threadIdx.x;
    __shared__ float red[256];
    float v0 = x[(size_t)r * ND + t];
    float v1 = x[(size_t)r * ND + 256 + t];
    float v2 = x[(size_t)r * ND + 512 + t];
    red[t] = v0 + v1 + v2;
    __syncthreads();
    for (int s = 128; s > 0; s >>= 1) { if (t < s) red[t] += red[t + s]; __syncthreads(); }
    float mean = red[0] * (1.0f / ND);
    __syncthreads();
    float d0 = v0 - mean, d1 = v1 - mean, d2 = v2 - mean;
    red[t] = d0 * d0 + d1 * d1 + d2 * d2;
    __syncthreads();
    for (int s = 128; s > 0; s >>= 1) { if (t < s) red[t] += red[t + s]; __syncthreads(); }
    float inv = 1.0f / sqrtf(red[0] * (1.0f / ND) + 1e-5f);
    y[(size_t)r * ND + t]       = d0 * inv * g[t]       + bb[t];
    y[(size_t)r * ND + 256 + t] = d1 * inv * g[256 + t] + bb[256 + t];
    y[(size_t)r * ND + 512 + t] = d2 * inv * g[512 + t] + bb[512 + t];
}

// attention scores + softmax: one block per (b,h)
__global__ void attn_scores_k(const float* __restrict__ Qp,
                              const float* __restrict__ Kb,
                              float* __restrict__ att)
{
    int bh = blockIdx.x;
    int b = bh >> 3, h = bh & 7;
    __shared__ float qs[NHD];
    __shared__ float sc[NTOK];
    __shared__ float red[256];
    int t = threadIdx.x;
    if (t < NHD) qs[t] = Qp[(size_t)b * ND + h * NHD + t];
    __syncthreads();
    const float scale = 0.1020620726159658f; // 1/sqrt(96)
    for (int k = t; k < NTOK; k += 256) {
        const float* kr = Kb + ((size_t)b * NTOK + k) * ND + h * NHD;
        float s = 0.f;
#pragma unroll 8
        for (int d = 0; d < NHD; d++) s = fmaf(qs[d], kr[d], s);
        sc[k] = s * scale;
    }
    __syncthreads();
    float m = -1e30f;
    for (int k = t; k < NTOK; k += 256) m = fmaxf(m, sc[k]);
    red[t] = m; __syncthreads();
    for (int s = 128; s > 0; s >>= 1) { if (t < s) red[t] = fmaxf(red[t], red[t + s]); __syncthreads(); }
    m = red[0]; __syncthreads();
    float sum = 0.f;
    for (int k = t; k < NTOK; k += 256) { float e = expf(sc[k] - m); sc[k] = e; sum += e; }
    red[t] = sum; __syncthreads();
    for (int s = 128; s > 0; s >>= 1) { if (t < s) red[t] += red[t + s]; __syncthreads(); }
    float inv = 1.0f / red[0];
    for (int k = t; k < NTOK; k += 256) att[(size_t)bh * NTOK + k] = sc[k] * inv;
}

// o[b, h*96+d] = sum_k att[b,h,k] * V[b,k,h*96+d]; one block (128 thr) per (b,h)
__global__ void attn_av_k(const float* __restrict__ att,
                          const float* __restrict__ Vb,
                          float* __restrict__ o)
{
    int bh = blockIdx.x;
    int b = bh >> 3, h = bh & 7;
    __shared__ float p[NTOK];
    int t = threadIdx.x;
    for (int k = t; k < NTOK; k += 128) p[k] = att[(size_t)bh * NTOK + k];
    __syncthreads();
    if (t < NHD) {
        const float* vp = Vb + (size_t)b * NTOK * ND + h * NHD + t;
        float acc = 0.f;
        for (int k = 0; k < NTOK; k++) acc = fmaf(p[k], vp[(size_t)k * ND], acc);
        o[(size_t)b * ND + h * NHD + t] = acc;
    }
}

// build q-init A matrix: [onehot(intent-1,3), past.flatten(96)] -> (32,99)
__global__ void build_qa_k(const int* __restrict__ intent,
                           const float* __restrict__ past,
                           float* __restrict__ qA)
{
    int idx = blockIdx.x * 256 + threadIdx.x;
    if (idx >= NB * 99) return;
    int b = idx / 99, j = idx - b * 99;
    float v;
    if (j < 3) v = (intent[b] - 1 == j) ? 1.f : 0.f;
    else       v = past[b * 96 + (j - 3)];
    qA[idx] = v;
}

// trajectory integration + controls; writes out0, out1, out5, out6
__global__ void integrate_k(const float* __restrict__ cp,
                            const float* __restrict__ past,
                            float* __restrict__ out)
{
    int idx = blockIdx.x * 256 + threadIdx.x;
    if (idx >= NB * NK) return;
    int b = idx / NK, k = idx - b * NK;
    const float* pl = past + b * 96 + 90; // past[b,15,:]
    float x = pl[0], y = pl[1], vx = pl[2], vy = pl[3];
    float s  = sqrtf(vx * vx + vy * vy + 1e-6f);
    float hd = atan2f(vy, vx);
    const float* cpk = cp + (size_t)b * 3000 + k * 60;
    float* o0 = out +        (size_t)b * 3000 + k * 60;
    float* o1 = out + 96000 + (size_t)b * 3000 + k * 60;
    float* c5 = out + 1946688 + (size_t)b * 3000 + k * 60;
    float* c6 = out + 2042688 + (size_t)b * 3000 + k * 60;
    const float DT = 0.25f;
    for (int t = 0; t < NT; t++) {
        float a = tanhf(cpk[t * 2 + 0]) * 8.0f;
        float w = tanhf(cpk[t * 2 + 1]) * 1.0f;
        x += s * cosf(hd) * DT;
        y += s * sinf(hd) * DT;
        o0[t * 2 + 0] = x; o0[t * 2 + 1] = y;
        o1[t * 2 + 0] = x; o1[t * 2 + 1] = y;
        c5[t * 2 + 0] = a; c5[t * 2 + 1] = w;
        c6[t * 2 + 0] = a; c6[t * 2 + 1] = w;
        hd += w * DT;
        s = fmaxf(s + a * DT, 0.f);
    }
}

// q_for_score broadcast: out2[(b*50+k)*768+d] = q[b*768+d]
__global__ void qscore_k(const float* __restrict__ q, float* __restrict__ out2)
{
    int idx = blockIdx.x * 256 + threadIdx.x;
    if (idx >= NB * NK * ND) return;
    int r = idx / ND, d = idx - r * ND;
    int b = r / NK;
    out2[idx] = q[(size_t)b * ND + d];
}

// concat [q_for_score, tf] -> (1600, 1536)
__global__ void cat_k(const float* __restrict__ q, const float* __restrict__ tf,
                      float* __restrict__ cat)
{
    int idx = blockIdx.x * 256 + threadIdx.x;
    if (idx >= NB * NK * 2 * ND) return;
    int r = idx / (2 * ND), c = idx - r * (2 * ND);
    int b = r / NK;
    cat[idx] = (c < ND) ? q[(size_t)b * ND + c] : tf[(size_t)r * ND + (c - ND)];
}

// scores[r] = sc2[r,:] @ sd3_w + sd3_b ; one wave per row
__global__ void score_k(const float* __restrict__ sc2, const float* __restrict__ w,
                        const float* __restrict__ bias, float* __restrict__ out)
{
    int r = blockIdx.x * 4 + (threadIdx.x >> 6);
    int lane = threadIdx.x & 63;
    if (r >= NB * NK) return;
    float acc = 0.f;
    for (int d = lane; d < ND; d += 64) acc = fmaf(sc2[(size_t)r * ND + d], w[d], acc);
    for (int off = 32; off > 0; off >>= 1) acc += __shfl_down(acc, off, 64);
    if (lane == 0) out[r] = acc + bias[0];
}

// ---------------------------------------------------------------------------
static inline void gemm(hipStream_t st, int amode, int bt, int act, int hasres,
                        const float* A, const float* Bw, const float* bias,
                        const float* res, float* C, int M, int N, int K,
                        int Cin = 0, int Hin = 0, int Win = 0, int hwS = 0, int wS = 0)
{
    dim3 blk(16, 16), grd((N + 63) / 64, (M + 63) / 64);
#define GO(AM, BT_, ACT_, RES_) \
    gemm_k<AM, BT_, ACT_, RES_><<<grd, blk, 0, st>>>(A, Bw, bias, res, C, M, N, K, Cin, Hin, Win, hwS, wS)
    if      (amode == 0 && act == 0 && !hasres) GO(0, 0, 0, 0);
    else if (amode == 0 && act == 0 &&  hasres) GO(0, 0, 0, 1);
    else if (amode == 0 && act == 1)            GO(0, 0, 1, 0);
    else if (amode == 1 && act == 1)            GO(1, 1, 1, 0);
    else if (amode == 1 && act == 0)            GO(1, 1, 0, 0);
    else if (amode == 2)                        GO(2, 1, 1, 0);
#undef GO
}

extern "C" void kernel_launch(void* const* d_in, const int* in_sizes, int n_in,
                              void* d_out, int out_size, void* d_ws, size_t ws_size,
                              hipStream_t stream)
{
    const float* feats_vit = (const float*)d_in[0];
    const float* past      = (const float*)d_in[1];
    const int*   intent    = (const int*)  d_in[2];
    const float* qi_w   = (const float*)d_in[3];
    const float* qi_b   = (const float*)d_in[4];
    const float* va1_w  = (const float*)d_in[5];
    const float* va1_b  = (const float*)d_in[6];
    const float* va2_w  = (const float*)d_in[7];
    const float* va2_b  = (const float*)d_in[8];
    const float* pos    = (const float*)d_in[9];
    const float* ln1_g  = (const float*)d_in[10];
    const float* ln1_b  = (const float*)d_in[11];
    const float* wq     = (const float*)d_in[12];
    const float* bq     = (const float*)d_in[13];
    const float* wk     = (const float*)d_in[14];
    const float* bk     = (const float*)d_in[15];
    const float* wv     = (const float*)d_in[16];
    const float* bv     = (const float*)d_in[17];
    const float* wo     = (const float*)d_in[18];
    const float* bo     = (const float*)d_in[19];
    const float* ln2_g  = (const float*)d_in[20];
    const float* ln2_b  = (const float*)d_in[21];
    const float* m1w    = (const float*)d_in[22];
    const float* m1b    = (const float*)d_in[23];
    const float* m2w    = (const float*)d_in[24];
    const float* m2b    = (const float*)d_in[25];
    const float* dg1w   = (const float*)d_in[26];
    const float* dg1b   = (const float*)d_in[27];
    const float* dg2w   = (const float*)d_in[28];
    const float* dg2b   = (const float*)d_in[29];
    const float* dg3w   = (const float*)d_in[30];
    const float* dg3b   = (const float*)d_in[31];
    const float* td1w   = (const float*)d_in[32];
    const float* td1b   = (const float*)d_in[33];
    const float* td2w   = (const float*)d_in[34];
    const float* td2b   = (const float*)d_in[35];
    const float* td3w   = (const float*)d_in[36];
    const float* td3b   = (const float*)d_in[37];
    const float* tf1w   = (const float*)d_in[38];
    const float* tf1b   = (const float*)d_in[39];
    const float* tf2w   = (const float*)d_in[40];
    const float* tf2b   = (const float*)d_in[41];
    const float* sd1w   = (const float*)d_in[42];
    const float* sd1b   = (const float*)d_in[43];
    const float* sd2w   = (const float*)d_in[44];
    const float* sd2b   = (const float*)d_in[45];
    const float* sd3w   = (const float*)d_in[46];
    const float* sd3b   = (const float*)d_in[47];

    float* out = (float*)d_out;
    float* ws  = (float*)d_ws;

    // workspace layout (floats)
    const size_t BIG = (size_t)NB * ND * NTOK;   // 25165824
    size_t off = 0;
    float* bufA = ws + off; off += BIG;          // conv1-out(gelu) -> tokens
    float* bufB = ws + off; off += BIG;          // conv2-out (feats) -> K -> V
    float* d1   = ws + off; off += (size_t)NB * 64 * 1024;
    float* d2   = ws + off; off += (size_t)NB * 32 * 4096;
    float* attb = ws + off; off += (size_t)NB * NKH * NTOK;
    float* q    = ws + off; off += NB * ND;
    float* qn   = ws + off; off += NB * ND;
    float* Qp   = ws + off; off += NB * ND;
    float* ob   = ws + off; off += NB * ND;
    float* hm   = ws + off; off += NB * NMLP;
    float* qA   = ws + off; off += NB * 128;
    float* h1   = ws + off; off += NB * ND;
    float* h2   = ws + off; off += NB * ND;
    float* cp   = ws + off; off += NB * 3000;
    float* tfa  = ws + off; off += (size_t)NB * NK * ND;
    float* tfb  = ws + off; off += (size_t)NB * NK * ND;
    float* catb = ws + off; off += (size_t)NB * NK * 2 * ND;
    float* s1   = ws + off; off += (size_t)NB * NK * ND;
    float* s2   = ws + off; off += (size_t)NB * NK * ND;
    (void)ws_size; (void)n_in; (void)in_sizes; (void)out_size;

    const int M_PIX = NB * 1024;   // 32768

    // feats_vit arrives NCHW; conv1's im2col expects NHWC.
    // Transpose it once into bufB (NHWC) using the tokens trick in reverse:
    // we instead fold the transpose into conv1 by treating feats_vit as NHWC
    // with (H,W,C) = ... not possible. Do an explicit transpose kernel:
    {
        // bufB[b, y, x, c] = feats_vit[b, c, y, x]
        // use a 32x32 tiled transpose over (c, n=y*32+x) per batch
        // (reuse old transpose-style kernel inline via lambda-less global below)
    }
    // ---- NCHW -> NHWC transpose for feats_vit ----
    {
        extern __global__ void nchw2nhwc_k(const float*, float*);
        nchw2nhwc_k<<<dim3(ND / 32, NTOK / 32, NB), dim3(32, 8), 0, stream>>>(feats_vit, bufB);
    }

    // ---- vision adapter: conv1 (gelu) -> conv2 ----
    gemm(stream, 1, 1, 1, 0, bufB, va1_w, va1_b, nullptr, bufA,
         M_PIX, ND, ND * 9, ND, 32, 32, 10, 5);
    gemm(stream, 1, 1, 0, 0, bufA, va2_w, va2_b, nullptr, bufB,
         M_PIX, ND, ND * 9, ND, 32, 32, 10, 5);

    // ---- depth branch (all NHWC) ----
    gemm(stream, 1, 1, 1, 0, bufB, dg1w, dg1b, nullptr, d1,
         M_PIX, 64, ND * 9, ND, 32, 32, 10, 5);
    gemm(stream, 2, 1, 1, 0, d1, dg2w, dg2b, nullptr, d2,
         NB * 4096, 32, 64 * 9, 64, 32, 32, 12, 6);
    depth_k<<<(NB * 16384 + 255) / 256, 256, 0, stream>>>(d2, dg3w, dg3b, out + 1422400);

    // ---- tokens = feats(NHWC==[b,n,d]) + pos_enc ----
    tokens_k<<<(NB * NTOK * ND / 4 + 255) / 256, 256, 0, stream>>>(bufB, pos, bufA);

    // ---- q init ----
    build_qa_k<<<(NB * 99 + 255) / 256, 256, 0, stream>>>(intent, past, qA);
    gemm(stream, 0, 0, 0, 0, qA, qi_w, qi_b, nullptr, q, NB, ND, 99);

    // ---- transformer layers ----
    for (int i = 0; i < NL; i++) {
        const size_t W = (size_t)i * ND * ND;
        ln_k<<<NB, 256, 0, stream>>>(q, ln1_g + i * ND, ln1_b + i * ND, qn);
        gemm(stream, 0, 0, 0, 0, qn, wq + W, bq + i * ND, nullptr, Qp, NB, ND, ND);
        gemm(stream, 0, 0, 0, 0, bufA, wk + W, bk + i * ND, nullptr, bufB, M_PIX, ND, ND);
        attn_scores_k<<<NB * NKH, 256, 0, stream>>>(Qp, bufB, attb);
        gemm(stream, 0, 0, 0, 0, bufA, wv + W, bv + i * ND, nullptr, bufB, M_PIX, ND, ND);
        attn_av_k<<<NB * NKH, 128, 0, stream>>>(attb, bufB, ob);
        gemm(stream, 0, 0, 0, 1, ob, wo + W, bo + i * ND, q, q, NB, ND, ND);
        ln_k<<<NB, 256, 0, stream>>>(q, ln2_g + i * ND, ln2_b + i * ND, qn);
        gemm(stream, 0, 0, 1, 0, qn, m1w + (size_t)i * ND * NMLP, m1b + i * NMLP,
             nullptr, hm, NB, NMLP, ND);
        gemm(stream, 0, 0, 0, 1, hm, m2w + (size_t)i * NMLP * ND, m2b + i * ND,
             q, q, NB, ND, NMLP);
    }

    // ---- trajectory decoder ----
    gemm(stream, 0, 0, 1, 0, q,  td1w, td1b, nullptr, h1, NB, ND, ND);
    gemm(stream, 0, 0, 1, 0, h1, td2w, td2b, nullptr, h2, NB, ND, ND);
    gemm(stream, 0, 0, 0, 0, h2, td3w, td3b, nullptr, cp, NB, 3000, ND);
    integrate_k<<<(NB * NK + 255) / 256, 256, 0, stream>>>(cp, past, out);

    // ---- score head ----
    qscore_k<<<(NB * NK * ND + 255) / 256, 256, 0, stream>>>(q, out + 192000);
    gemm(stream, 0, 0, 1, 0, out, tf1w, tf1b, nullptr, tfa, NB * NK, ND, 60);
    gemm(stream, 0, 0, 1, 0, tfa, tf2w, tf2b, nullptr, tfb, NB * NK, ND, ND);
    cat_k<<<(NB * NK * 2 * ND + 255) / 256, 256, 0, stream>>>(q, tfb, catb);
    gemm(stream, 0, 0, 1, 0, catb, sd1w, sd1b, nullptr, s1, NB * NK, ND, 2 * ND);
    gemm(stream, 0, 0, 1, 0, s1, sd2w, sd2b, nullptr, s2, NB * NK, ND, ND);
    score_k<<<(NB * NK + 3) / 4, 256, 0, stream>>>(s2, sd3w, sd3b, out + 1420800);
}

// bufB[b, y, x, c] = feats_vit[b, c, y, x]  — 32x32 LDS-tiled transpose
__global__ void nchw2nhwc_k(const float* __restrict__ src, float* __restrict__ dst)
{
    __shared__ float tile[32][33];
    int b = blockIdx.z, n0 = blockIdx.y * 32, c0 = blockIdx.x * 32;
    int tx = threadIdx.x, ty = threadIdx.y;
#pragma unroll
    for (int i = ty; i < 32; i += 8)
        tile[i][tx] = src[((size_t)b * ND + c0 + i) * NTOK + n0 + tx];
    __syncthreads();
#pragma unroll
    for (int i = ty; i < 32; i += 8)
        dst[((size_t)b * NTOK + n0 + i) * ND + c0 + tx] = tile[tx][i];
}

// Round 3
// 8480.269 us; speedup vs baseline: 3.2118x; 3.2118x over previous
//
#include <hip/hip_runtime.h>
#include <hip/hip_bf16.h>
#include <math.h>

// ---------------------------------------------------------------------------
// DeepMonocularModel — r3: conv1/conv2 + K/V projections on bf16 MFMA
// (m97 structure: 128x128 tile, BK=32, 16x16x32_bf16, global_load_lds w=16).
// Activations flow in zero-padded NHWC bf16 [b][34][34][768] so im2col is
// branch-free and K-slabs are contiguous (K order = tap*768 + ci).
// Everything else stays fp32 from r2 (passed, absmax 0.125).
// ---------------------------------------------------------------------------

#define NB   32
#define ND   768
#define NTOK 1024
#define NKH  8
#define NHD  96
#define NL   4
#define NMLP 3072
#define NK   50
#define NT   30

typedef short  s8v __attribute__((ext_vector_type(8)));
typedef float  f4v __attribute__((ext_vector_type(4)));

__device__ __forceinline__ float gelu_f(float x) {
    return 0.5f * x * (1.0f + erff(x * 0.70710678118654752f));
}
__device__ __forceinline__ float softplus_f(float x) {
    return x > 0.f ? x + log1pf(expf(-x)) : log1pf(expf(x));
}
__device__ __forceinline__ void gld_lds16(const void* g, void* l) {
    __builtin_amdgcn_global_load_lds(
        (const __attribute__((address_space(1))) void*)g,
        (__attribute__((address_space(3))) void*)l, 16, 0, 0);
}

// ---------------------------------------------------------------------------
// bf16 MFMA GEMM, C[M,N] = act(A_view @ Bt^T + bias)
// AMODE 0: A plain bf16 [M][K]
// AMODE 1: A padded NHWC bf16 [b][34][34][768], 3x3 conv, K = tap*768+ci
// Bt: bf16 [N][K]
// OUT 0: fp32 C[m*N+n]  |  OUT 1: bf16 into padded NHWC (conv intermediate)
// ACT 0 none | 1 gelu
// Requires M%128==0, N%128==0, K%32==0 (and K%768==0 slabs stay in one tap).
// ---------------------------------------------------------------------------
template<int AMODE, int ACT, int OUT>
__global__ __launch_bounds__(256) void mfma_gemm_k(
    const __hip_bfloat16* __restrict__ A,
    const __hip_bfloat16* __restrict__ Bt,
    const float* __restrict__ bias,
    float* __restrict__ Cf,
    __hip_bfloat16* __restrict__ Cpad,
    int M, int N, int K)
{
    __shared__ __hip_bfloat16 As[128 * 32];
    __shared__ __hip_bfloat16 Bs[128 * 32];
    const int tid  = threadIdx.x;
    const int lane = tid & 63;
    const int wave = tid >> 6;
    const int wm = wave >> 1, wn = wave & 1;
    const int bm = blockIdx.y * 128, bn = blockIdx.x * 128;
    const int r0 = tid >> 2;          // staging row (0..63)
    const int kb = (tid & 3) * 8;     // staging k-offset in elements

    f4v acc[4][4];
#pragma unroll
    for (int i = 0; i < 4; i++)
#pragma unroll
        for (int j = 0; j < 4; j++) acc[i][j] = (f4v)0.f;

    int rr = 0, kin = 0;              // AMODE1: tap index, channel offset
    for (int k0 = 0; k0 < K; k0 += 32) {
        // ---- stage A (two 64-row chunks) ----
#pragma unroll
        for (int c = 0; c < 2; c++) {
            const int row = r0 + c * 64;
            const __hip_bfloat16* ga;
            if constexpr (AMODE == 0) {
                ga = A + (size_t)(bm + row) * K + k0 + kb;
            } else {
                int gm = bm + row;
                int b = gm >> 10, y = (gm >> 5) & 31, x = gm & 31;
                int dy = rr / 3, dx = rr - dy * 3;   // 0..2 each; pad +1 folds in
                ga = A + ((((size_t)b * 34 + y + dy) * 34 + (x + dx)) * 768 + kin + kb);
            }
            gld_lds16(ga, &As[row * 32 + kb]);
        }
        // ---- stage B ----
#pragma unroll
        for (int c = 0; c < 2; c++) {
            const int row = r0 + c * 64;
            gld_lds16(Bt + (size_t)(bn + row) * K + k0 + kb, &Bs[row * 32 + kb]);
        }
        __syncthreads();
        // ---- compute ----
        const int koff = (lane >> 4) * 8;
        s8v af[4], bfv[4];
#pragma unroll
        for (int i = 0; i < 4; i++)
            af[i] = *(const s8v*)(&As[(wm * 64 + i * 16 + (lane & 15)) * 32 + koff]);
#pragma unroll
        for (int j = 0; j < 4; j++)
            bfv[j] = *(const s8v*)(&Bs[(wn * 64 + j * 16 + (lane & 15)) * 32 + koff]);
#pragma unroll
        for (int i = 0; i < 4; i++)
#pragma unroll
            for (int j = 0; j < 4; j++)
                acc[i][j] = __builtin_amdgcn_mfma_f32_16x16x32_bf16(af[i], bfv[j], acc[i][j], 0, 0, 0);
        __syncthreads();
        if constexpr (AMODE == 1) { kin += 32; if (kin == 768) { kin = 0; rr++; } }
    }
    // ---- epilogue: C/D layout col=lane&15, row=(lane>>4)*4+reg ----
#pragma unroll
    for (int i = 0; i < 4; i++) {
        const int mbase = bm + wm * 64 + i * 16 + ((lane >> 4) << 2);
#pragma unroll
        for (int j = 0; j < 4; j++) {
            const int n = bn + wn * 64 + j * 16 + (lane & 15);
            const float bs = bias[n];
#pragma unroll
            for (int g = 0; g < 4; g++) {
                const int m = mbase + g;
                float v = acc[i][j][g] + bs;
                if constexpr (ACT == 1) v = gelu_f(v);
                if constexpr (OUT == 0) {
                    Cf[(size_t)m * N + n] = v;
                } else {
                    int b = m >> 10, y = (m >> 5) & 31, x = m & 31;
                    Cpad[(((size_t)b * 34 + y + 1) * 34 + (x + 1)) * 768 + n] =
                        __float2bfloat16(v);
                }
            }
        }
    }
}

// NCHW fp32 -> padded NHWC bf16 interior (32x32 LDS-tiled transpose)
__global__ void nchw2pad_bf_k(const float* __restrict__ src, __hip_bfloat16* __restrict__ dst)
{
    __shared__ float tile[32][33];
    int b = blockIdx.z, n0 = blockIdx.y * 32, c0 = blockIdx.x * 32;
    int tx = threadIdx.x, ty = threadIdx.y;
#pragma unroll
    for (int i = ty; i < 32; i += 8)
        tile[i][tx] = src[((size_t)b * ND + c0 + i) * NTOK + n0 + tx];
    __syncthreads();
#pragma unroll
    for (int i = ty; i < 32; i += 8) {
        int n = n0 + i, y = n >> 5, x = n & 31;
        dst[(((size_t)b * 34 + y + 1) * 34 + (x + 1)) * 768 + c0 + tx] =
            __float2bfloat16(tile[tx][i]);
    }
}

// zero the borders of both padded bf16 buffers (ws is poisoned each call)
__global__ void pad_border_k(__hip_bfloat16* __restrict__ p1, __hip_bfloat16* __restrict__ p2)
{
    int idx = blockIdx.x * 256 + threadIdx.x;   // 32 b * 132 cells * 192 (4-el groups)
    if (idx >= 32 * 132 * 192) return;
    int c4 = idx % 192;
    int cell = (idx / 192) % 132;
    int b = idx / (192 * 132);
    int yy, xx;
    if      (cell < 34)  { yy = 0;  xx = cell; }
    else if (cell < 68)  { yy = 33; xx = cell - 34; }
    else if (cell < 100) { yy = cell - 68 + 1;  xx = 0; }
    else                 { yy = cell - 100 + 1; xx = 33; }
    size_t o = (((size_t)b * 34 + yy) * 34 + xx) * 768 + c4 * 4;
    *reinterpret_cast<uint2*>(p1 + o) = make_uint2(0u, 0u);
    *reinterpret_cast<uint2*>(p2 + o) = make_uint2(0u, 0u);
}

// conv weight OIHW fp32 -> bf16 [n][tap*768+ci]
__global__ void convw_bf_k(const float* __restrict__ w, __hip_bfloat16* __restrict__ wT)
{
    int idx = blockIdx.x * 256 + threadIdx.x;
    if (idx >= 768 * 6912) return;
    int n = idx / 6912, k = idx - n * 6912;
    int r = k / 768, ci = k - r * 768;
    wT[idx] = __float2bfloat16(w[((size_t)n * 768 + ci) * 9 + r]);
}

// [K][N] fp32 -> [N][K] bf16 (768x768), tiled transpose
__global__ void wkv_bf_k(const float* __restrict__ w, __hip_bfloat16* __restrict__ wT)
{
    __shared__ float t[32][33];
    int k0 = blockIdx.y * 32, n0 = blockIdx.x * 32;
    int tx = threadIdx.x, ty = threadIdx.y;
#pragma unroll
    for (int i = ty; i < 32; i += 8)
        t[i][tx] = w[(size_t)(k0 + i) * 768 + n0 + tx];
    __syncthreads();
#pragma unroll
    for (int i = ty; i < 32; i += 8)
        wT[(size_t)(n0 + i) * 768 + k0 + tx] = __float2bfloat16(t[tx][i]);
}

// tokens bf16 = bf16(feats_nhwc + pos)
__global__ void tokens_bf_k(const float* __restrict__ f, const float* __restrict__ pos,
                            __hip_bfloat16* __restrict__ tok)
{
    size_t i = ((size_t)blockIdx.x * 256 + threadIdx.x) * 4;
    if (i >= (size_t)NB * NTOK * ND) return;
    const float4 a = *reinterpret_cast<const float4*>(f + i);
    const float4 p = *reinterpret_cast<const float4*>(pos + (i & (NTOK * ND - 1)));
    tok[i + 0] = __float2bfloat16(a.x + p.x);
    tok[i + 1] = __float2bfloat16(a.y + p.y);
    tok[i + 2] = __float2bfloat16(a.z + p.z);
    tok[i + 3] = __float2bfloat16(a.w + p.w);
}

// ---------------------------------------------------------------------------
// fp32 tiled GEMM (r2) — still used for dg1/dg2 and all small GEMMs
// ---------------------------------------------------------------------------
template<int AMODE, int BT, int ACT, int RES>
__global__ __launch_bounds__(256) void gemm_k(
    const float* __restrict__ A, const float* __restrict__ Bw,
    const float* __restrict__ bias, const float* __restrict__ res,
    float* __restrict__ C, int M, int N, int K,
    int Cin, int Hin, int Win, int hwShift, int wShift)
{
    __shared__ float As[16][68];
    __shared__ float Bs[16][68];
    const int tx = threadIdx.x, ty = threadIdx.y;
    const int tid = ty * 16 + tx;
    const int bm = blockIdx.y * 64, bn = blockIdx.x * 64;
    float acc[4][4] = {};

    for (int k0 = 0; k0 < K; k0 += 16) {
#pragma unroll
        for (int i = 0; i < 4; i++) {
            int idx = i * 256 + tid;
            int ml = idx >> 4, kl = idx & 15;
            int m = bm + ml, k = k0 + kl;
            float v = 0.f;
            if (m < M && k < K) {
                if constexpr (AMODE == 0) {
                    v = A[(size_t)m * K + k];
                } else {
                    int b   = m >> hwShift;
                    int rem = m & ((1 << hwShift) - 1);
                    int y   = rem >> wShift;
                    int x   = rem & ((1 << wShift) - 1);
                    int ci  = k / 9;
                    int r   = k - ci * 9;
                    int yy  = y + r / 3 - 1;
                    int xx  = x + r % 3 - 1;
                    int Wo  = 1 << wShift;
                    int Ho  = 1 << (hwShift - wShift);
                    if (yy >= 0 && yy < Ho && xx >= 0 && xx < Wo) {
                        int iy = yy, ix = xx;
                        if constexpr (AMODE == 2) { iy = yy >> 1; ix = xx >> 1; }
                        v = A[(((size_t)b * Hin + iy) * Win + ix) * Cin + ci];
                    }
                }
            }
            As[kl][ml] = v;
        }
#pragma unroll
        for (int i = 0; i < 4; i++) {
            int idx = i * 256 + tid;
            int kl, nl;
            if constexpr (BT == 0) { nl = idx & 63; kl = idx >> 6; }
            else                   { kl = idx & 15; nl = idx >> 4; }
            int k = k0 + kl, n = bn + nl;
            float v = 0.f;
            if (k < K && n < N)
                v = (BT == 0) ? Bw[(size_t)k * N + n] : Bw[(size_t)n * K + k];
            Bs[kl][nl] = v;
        }
        __syncthreads();
#pragma unroll
        for (int kk = 0; kk < 16; kk++) {
            const float4 av = *reinterpret_cast<const float4*>(&As[kk][ty * 4]);
            const float4 bv = *reinterpret_cast<const float4*>(&Bs[kk][tx * 4]);
            const float a4[4] = {av.x, av.y, av.z, av.w};
            const float b4[4] = {bv.x, bv.y, bv.z, bv.w};
#pragma unroll
            for (int i = 0; i < 4; i++)
#pragma unroll
                for (int j = 0; j < 4; j++)
                    acc[i][j] = fmaf(a4[i], b4[j], acc[i][j]);
        }
        __syncthreads();
    }
#pragma unroll
    for (int i = 0; i < 4; i++) {
        int m = bm + ty * 4 + i;
        if (m >= M) continue;
#pragma unroll
        for (int j = 0; j < 4; j++) {
            int n = bn + tx * 4 + j;
            if (n >= N) continue;
            float v = acc[i][j] + bias[n];
            if constexpr (ACT == 1) v = gelu_f(v);
            if constexpr (RES == 1) v += res[(size_t)m * N + n];
            C[(size_t)m * N + n] = v;
        }
    }
}

// depth[b,y,x] = softplus(dot(d2_nhwc[b,y/2,x/2,:], w3) + b3)
__global__ void depth_k(const float* __restrict__ d2,
                        const float* __restrict__ w3, const float* __restrict__ b3,
                        float* __restrict__ out)
{
    int idx = blockIdx.x * 256 + threadIdx.x;
    if (idx >= NB * 128 * 128) return;
    int b = idx >> 14;
    int rem = idx & 16383;
    int y = rem >> 7, x = rem & 127;
    const float* base = d2 + (((size_t)b * 64 + (y >> 1)) * 64 + (x >> 1)) * 32;
    float acc = b3[0];
#pragma unroll
    for (int ci = 0; ci < 32; ci++) acc = fmaf(base[ci], w3[ci], acc);
    out[idx] = softplus_f(acc);
}

__global__ void ln_k(const float* __restrict__ x, const float* __restrict__ g,
                     const float* __restrict__ bb, float* __restrict__ y)
{
    int r = blockIdx.x, t = threadIdx.x;
    __shared__ float red[256];
    float v0 = x[(size_t)r * ND + t];
    float v1 = x[(size_t)r * ND + 256 + t];
    float v2 = x[(size_t)r * ND + 512 + t];
    red[t] = v0 + v1 + v2;
    __syncthreads();
    for (int s = 128; s > 0; s >>= 1) { if (t < s) red[t] += red[t + s]; __syncthreads(); }
    float mean = red[0] * (1.0f / ND);
    __syncthreads();
    float d0 = v0 - mean, d1 = v1 - mean, d2 = v2 - mean;
    red[t] = d0 * d0 + d1 * d1 + d2 * d2;
    __syncthreads();
    for (int s = 128; s > 0; s >>= 1) { if (t < s) red[t] += red[t + s]; __syncthreads(); }
    float inv = 1.0f / sqrtf(red[0] * (1.0f / ND) + 1e-5f);
    y[(size_t)r * ND + t]       = d0 * inv * g[t]       + bb[t];
    y[(size_t)r * ND + 256 + t] = d1 * inv * g[256 + t] + bb[256 + t];
    y[(size_t)r * ND + 512 + t] = d2 * inv * g[512 + t] + bb[512 + t];
}

__global__ void attn_scores_k(const float* __restrict__ Qp,
                              const float* __restrict__ Kb,
                              float* __restrict__ att)
{
    int bh = blockIdx.x;
    int b = bh >> 3, h = bh & 7;
    __shared__ float qs[NHD];
    __shared__ float sc[NTOK];
    __shared__ float red[256];
    int t = threadIdx.x;
    if (t < NHD) qs[t] = Qp[(size_t)b * ND + h * NHD + t];
    __syncthreads();
    const float scale = 0.1020620726159658f;
    for (int k = t; k < NTOK; k += 256) {
        const float* kr = Kb + ((size_t)b * NTOK + k) * ND + h * NHD;
        float s = 0.f;
#pragma unroll 8
        for (int d = 0; d < NHD; d++) s = fmaf(qs[d], kr[d], s);
        sc[k] = s * scale;
    }
    __syncthreads();
    float m = -1e30f;
    for (int k = t; k < NTOK; k += 256) m = fmaxf(m, sc[k]);
    red[t] = m; __syncthreads();
    for (int s = 128; s > 0; s >>= 1) { if (t < s) red[t] = fmaxf(red[t], red[t + s]); __syncthreads(); }
    m = red[0]; __syncthreads();
    float sum = 0.f;
    for (int k = t; k < NTOK; k += 256) { float e = expf(sc[k] - m); sc[k] = e; sum += e; }
    red[t] = sum; __syncthreads();
    for (int s = 128; s > 0; s >>= 1) { if (t < s) red[t] += red[t + s]; __syncthreads(); }
    float inv = 1.0f / red[0];
    for (int k = t; k < NTOK; k += 256) att[(size_t)bh * NTOK + k] = sc[k] * inv;
}

__global__ void attn_av_k(const float* __restrict__ att,
                          const float* __restrict__ Vb,
                          float* __restrict__ o)
{
    int bh = blockIdx.x;
    int b = bh >> 3, h = bh & 7;
    __shared__ float p[NTOK];
    int t = threadIdx.x;
    for (int k = t; k < NTOK; k += 128) p[k] = att[(size_t)bh * NTOK + k];
    __syncthreads();
    if (t < NHD) {
        const float* vp = Vb + (size_t)b * NTOK * ND + h * NHD + t;
        float acc = 0.f;
        for (int k = 0; k < NTOK; k++) acc = fmaf(p[k], vp[(size_t)k * ND], acc);
        o[(size_t)b * ND + h * NHD + t] = acc;
    }
}

__global__ void build_qa_k(const int* __restrict__ intent,
                           const float* __restrict__ past,
                           float* __restrict__ qA)
{
    int idx = blockIdx.x * 256 + threadIdx.x;
    if (idx >= NB * 99) return;
    int b = idx / 99, j = idx - b * 99;
    float v;
    if (j < 3) v = (intent[b] - 1 == j) ? 1.f : 0.f;
    else       v = past[b * 96 + (j - 3)];
    qA[idx] = v;
}

__global__ void integrate_k(const float* __restrict__ cp,
                            const float* __restrict__ past,
                            float* __restrict__ out)
{
    int idx = blockIdx.x * 256 + threadIdx.x;
    if (idx >= NB * NK) return;
    int b = idx / NK, k = idx - b * NK;
    const float* pl = past + b * 96 + 90;
    float x = pl[0], y = pl[1], vx = pl[2], vy = pl[3];
    float s  = sqrtf(vx * vx + vy * vy + 1e-6f);
    float hd = atan2f(vy, vx);
    const float* cpk = cp + (size_t)b * 3000 + k * 60;
    float* o0 = out +        (size_t)b * 3000 + k * 60;
    float* o1 = out + 96000 + (size_t)b * 3000 + k * 60;
    float* c5 = out + 1946688 + (size_t)b * 3000 + k * 60;
    float* c6 = out + 2042688 + (size_t)b * 3000 + k * 60;
    const float DT = 0.25f;
    for (int t = 0; t < NT; t++) {
        float a = tanhf(cpk[t * 2 + 0]) * 8.0f;
        float w = tanhf(cpk[t * 2 + 1]) * 1.0f;
        x += s * cosf(hd) * DT;
        y += s * sinf(hd) * DT;
        o0[t * 2 + 0] = x; o0[t * 2 + 1] = y;
        o1[t * 2 + 0] = x; o1[t * 2 + 1] = y;
        c5[t * 2 + 0] = a; c5[t * 2 + 1] = w;
        c6[t * 2 + 0] = a; c6[t * 2 + 1] = w;
        hd += w * DT;
        s = fmaxf(s + a * DT, 0.f);
    }
}

__global__ void qscore_k(const float* __restrict__ q, float* __restrict__ out2)
{
    int idx = blockIdx.x * 256 + threadIdx.x;
    if (idx >= NB * NK * ND) return;
    int r = idx / ND, d = idx - r * ND;
    int b = r / NK;
    out2[idx] = q[(size_t)b * ND + d];
}

__global__ void cat_k(const float* __restrict__ q, const float* __restrict__ tf,
                      float* __restrict__ cat)
{
    int idx = blockIdx.x * 256 + threadIdx.x;
    if (idx >= NB * NK * 2 * ND) return;
    int r = idx / (2 * ND), c = idx - r * (2 * ND);
    int b = r / NK;
    cat[idx] = (c < ND) ? q[(size_t)b * ND + c] : tf[(size_t)r * ND + (c - ND)];
}

__global__ void score_k(const float* __restrict__ sc2, const float* __restrict__ w,
                        const float* __restrict__ bias, float* __restrict__ out)
{
    int r = blockIdx.x * 4 + (threadIdx.x >> 6);
    int lane = threadIdx.x & 63;
    if (r >= NB * NK) return;
    float acc = 0.f;
    for (int d = lane; d < ND; d += 64) acc = fmaf(sc2[(size_t)r * ND + d], w[d], acc);
    for (int off = 32; off > 0; off >>= 1) acc += __shfl_down(acc, off, 64);
    if (lane == 0) out[r] = acc + bias[0];
}

// ---------------------------------------------------------------------------
static inline void gemm(hipStream_t st, int amode, int bt, int act, int hasres,
                        const float* A, const float* Bw, const float* bias,
                        const float* res, float* C, int M, int N, int K,
                        int Cin = 0, int Hin = 0, int Win = 0, int hwS = 0, int wS = 0)
{
    dim3 blk(16, 16), grd((N + 63) / 64, (M + 63) / 64);
#define GO(AM, BT_, ACT_, RES_) \
    gemm_k<AM, BT_, ACT_, RES_><<<grd, blk, 0, st>>>(A, Bw, bias, res, C, M, N, K, Cin, Hin, Win, hwS, wS)
    if      (amode == 0 && act == 0 && !hasres) GO(0, 0, 0, 0);
    else if (amode == 0 && act == 0 &&  hasres) GO(0, 0, 0, 1);
    else if (amode == 0 && act == 1)            GO(0, 0, 1, 0);
    else if (amode == 1 && act == 1)            GO(1, 1, 1, 0);
    else if (amode == 1 && act == 0)            GO(1, 1, 0, 0);
    else if (amode == 2)                        GO(2, 1, 1, 0);
#undef GO
}

extern "C" void kernel_launch(void* const* d_in, const int* in_sizes, int n_in,
                              void* d_out, int out_size, void* d_ws, size_t ws_size,
                              hipStream_t stream)
{
    const float* feats_vit = (const float*)d_in[0];
    const float* past      = (const float*)d_in[1];
    const int*   intent    = (const int*)  d_in[2];
    const float* qi_w   = (const float*)d_in[3];
    const float* qi_b   = (const float*)d_in[4];
    const float* va1_w  = (const float*)d_in[5];
    const float* va1_b  = (const float*)d_in[6];
    const float* va2_w  = (const float*)d_in[7];
    const float* va2_b  = (const float*)d_in[8];
    const float* pos    = (const float*)d_in[9];
    const float* ln1_g  = (const float*)d_in[10];
    const float* ln1_b  = (const float*)d_in[11];
    const float* wq     = (const float*)d_in[12];
    const float* bq     = (const float*)d_in[13];
    const float* wk     = (const float*)d_in[14];
    const float* bk     = (const float*)d_in[15];
    const float* wv     = (const float*)d_in[16];
    const float* bv     = (const float*)d_in[17];
    const float* wo     = (const float*)d_in[18];
    const float* bo     = (const float*)d_in[19];
    const float* ln2_g  = (const float*)d_in[20];
    const float* ln2_b  = (const float*)d_in[21];
    const float* m1w    = (const float*)d_in[22];
    const float* m1b    = (const float*)d_in[23];
    const float* m2w    = (const float*)d_in[24];
    const float* m2b    = (const float*)d_in[25];
    const float* dg1w   = (const float*)d_in[26];
    const float* dg1b   = (const float*)d_in[27];
    const float* dg2w   = (const float*)d_in[28];
    const float* dg2b   = (const float*)d_in[29];
    const float* dg3w   = (const float*)d_in[30];
    const float* dg3b   = (const float*)d_in[31];
    const float* td1w   = (const float*)d_in[32];
    const float* td1b   = (const float*)d_in[33];
    const float* td2w   = (const float*)d_in[34];
    const float* td2b   = (const float*)d_in[35];
    const float* td3w   = (const float*)d_in[36];
    const float* td3b   = (const float*)d_in[37];
    const float* tf1w   = (const float*)d_in[38];
    const float* tf1b   = (const float*)d_in[39];
    const float* tf2w   = (const float*)d_in[40];
    const float* tf2b   = (const float*)d_in[41];
    const float* sd1w   = (const float*)d_in[42];
    const float* sd1b   = (const float*)d_in[43];
    const float* sd2w   = (const float*)d_in[44];
    const float* sd2b   = (const float*)d_in[45];
    const float* sd3w   = (const float*)d_in[46];
    const float* sd3b   = (const float*)d_in[47];

    float* out = (float*)d_out;
    float* ws  = (float*)d_ws;

    // workspace layout (float units; bf16 buffers carved as float halves)
    size_t off = 0;
    float* bufB   = ws + off; off += (size_t)NB * ND * NTOK;        // feats fp32 NHWC -> K -> V
    float* xpad_f = ws + off; off += 14201856;                      // [32][34][34][768] bf16
    float* c1pad_f= ws + off; off += 14201856;                      // conv1 out, padded bf16
    float* wTc_f  = ws + off; off += 2654208;                       // conv weight bf16 [768][6912]
    float* wkT_f  = ws + off; off += 294912;                        // per-layer wk^T bf16
    float* wvT_f  = ws + off; off += 294912;
    float* d1     = ws + off; off += (size_t)NB * 64 * 1024;
    float* d2     = ws + off; off += (size_t)NB * 32 * 4096;
    float* attb   = ws + off; off += (size_t)NB * NKH * NTOK;
    float* q      = ws + off; off += NB * ND;
    float* qn     = ws + off; off += NB * ND;
    float* Qp     = ws + off; off += NB * ND;
    float* ob     = ws + off; off += NB * ND;
    float* hm     = ws + off; off += NB * NMLP;
    float* qA     = ws + off; off += NB * 128;
    float* h1     = ws + off; off += NB * ND;
    float* h2     = ws + off; off += NB * ND;
    float* cp     = ws + off; off += NB * 3000;
    // aliases (lifetimes disjoint from the padded conv buffers):
    __hip_bfloat16* xpad  = (__hip_bfloat16*)xpad_f;
    __hip_bfloat16* c1pad = (__hip_bfloat16*)c1pad_f;
    __hip_bfloat16* wTc   = (__hip_bfloat16*)wTc_f;
    __hip_bfloat16* wkT   = (__hip_bfloat16*)wkT_f;
    __hip_bfloat16* wvT   = (__hip_bfloat16*)wvT_f;
    __hip_bfloat16* tokbf = (__hip_bfloat16*)xpad_f;                // reuse after conv1
    float* tfa  = c1pad_f;                                          // reuse after conv2
    float* tfb  = c1pad_f + 1228800;
    float* catb = c1pad_f + 2457600;
    float* s1   = c1pad_f + 4915200;
    float* s2   = c1pad_f + 6144000;
    (void)ws_size; (void)n_in; (void)in_sizes; (void)out_size;

    const int M_PIX = NB * 1024;

    // ---- prepare padded bf16 input + conv weights ----
    pad_border_k<<<(32 * 132 * 192 + 255) / 256, 256, 0, stream>>>(xpad, c1pad);
    nchw2pad_bf_k<<<dim3(ND / 32, NTOK / 32, NB), dim3(32, 8), 0, stream>>>(feats_vit, xpad);
    convw_bf_k<<<(768 * 6912 + 255) / 256, 256, 0, stream>>>(va1_w, wTc);

    // ---- conv1 (bf16 MFMA, gelu, -> padded bf16) ----
    mfma_gemm_k<1, 1, 1><<<dim3(6, 256), 256, 0, stream>>>(
        xpad, wTc, va1_b, nullptr, c1pad, M_PIX, ND, ND * 9);
    convw_bf_k<<<(768 * 6912 + 255) / 256, 256, 0, stream>>>(va2_w, wTc);
    // ---- conv2 (bf16 MFMA, -> fp32 NHWC feats) ----
    mfma_gemm_k<1, 0, 0><<<dim3(6, 256), 256, 0, stream>>>(
        c1pad, wTc, va2_b, bufB, nullptr, M_PIX, ND, ND * 9);

    // ---- depth branch (fp32, NHWC) ----
    gemm(stream, 1, 1, 1, 0, bufB, dg1w, dg1b, nullptr, d1,
         M_PIX, 64, ND * 9, ND, 32, 32, 10, 5);
    gemm(stream, 2, 1, 1, 0, d1, dg2w, dg2b, nullptr, d2,
         NB * 4096, 32, 64 * 9, 64, 32, 32, 12, 6);
    depth_k<<<(NB * 16384 + 255) / 256, 256, 0, stream>>>(d2, dg3w, dg3b, out + 1422400);

    // ---- tokens (bf16) = feats + pos ----
    tokens_bf_k<<<(NB * NTOK * ND / 4 + 255) / 256, 256, 0, stream>>>(bufB, pos, tokbf);

    // ---- q init ----
    build_qa_k<<<(NB * 99 + 255) / 256, 256, 0, stream>>>(intent, past, qA);
    gemm(stream, 0, 0, 0, 0, qA, qi_w, qi_b, nullptr, q, NB, ND, 99);

    // ---- transformer layers ----
    for (int i = 0; i < NL; i++) {
        const size_t W = (size_t)i * ND * ND;
        ln_k<<<NB, 256, 0, stream>>>(q, ln1_g + i * ND, ln1_b + i * ND, qn);
        gemm(stream, 0, 0, 0, 0, qn, wq + W, bq + i * ND, nullptr, Qp, NB, ND, ND);
        // K projection (bf16 MFMA) -> bufB, scores+softmax
        wkv_bf_k<<<dim3(24, 24), dim3(32, 8), 0, stream>>>(wk + W, wkT);
        mfma_gemm_k<0, 0, 0><<<dim3(6, 256), 256, 0, stream>>>(
            tokbf, wkT, bk + i * ND, bufB, nullptr, M_PIX, ND, ND);
        attn_scores_k<<<NB * NKH, 256, 0, stream>>>(Qp, bufB, attb);
        // V projection (bf16 MFMA) -> bufB (overwrite K), att @ V
        wkv_bf_k<<<dim3(24, 24), dim3(32, 8), 0, stream>>>(wv + W, wvT);
        mfma_gemm_k<0, 0, 0><<<dim3(6, 256), 256, 0, stream>>>(
            tokbf, wvT, bv + i * ND, bufB, nullptr, M_PIX, ND, ND);
        attn_av_k<<<NB * NKH, 128, 0, stream>>>(attb, bufB, ob);
        gemm(stream, 0, 0, 0, 1, ob, wo + W, bo + i * ND, q, q, NB, ND, ND);
        ln_k<<<NB, 256, 0, stream>>>(q, ln2_g + i * ND, ln2_b + i * ND, qn);
        gemm(stream, 0, 0, 1, 0, qn, m1w + (size_t)i * ND * NMLP, m1b + i * NMLP,
             nullptr, hm, NB, NMLP, ND);
        gemm(stream, 0, 0, 0, 1, hm, m2w + (size_t)i * NMLP * ND, m2b + i * ND,
             q, q, NB, ND, NMLP);
    }

    // ---- trajectory decoder ----
    gemm(stream, 0, 0, 1, 0, q,  td1w, td1b, nullptr, h1, NB, ND, ND);
    gemm(stream, 0, 0, 1, 0, h1, td2w, td2b, nullptr, h2, NB, ND, ND);
    gemm(stream, 0, 0, 0, 0, h2, td3w, td3b, nullptr, cp, NB, 3000, ND);
    integrate_k<<<(NB * NK + 255) / 256, 256, 0, stream>>>(cp, past, out);

    // ---- score head ----
    qscore_k<<<(NB * NK * ND + 255) / 256, 256, 0, stream>>>(q, out + 192000);
    gemm(stream, 0, 0, 1, 0, out, tf1w, tf1b, nullptr, tfa, NB * NK, ND, 60);
    gemm(stream, 0, 0, 1, 0, tfa, tf2w, tf2b, nullptr, tfb, NB * NK, ND, ND);
    cat_k<<<(NB * NK * 2 * ND + 255) / 256, 256, 0, stream>>>(q, tfb, catb);
    gemm(stream, 0, 0, 1, 0, catb, sd1w, sd1b, nullptr, s1, NB * NK, ND, 2 * ND);
    gemm(stream, 0, 0, 1, 0, s1, sd2w, sd2b, nullptr, s2, NB * NK, ND, ND);
    score_k<<<(NB * NK + 3) / 4, 256, 0, stream>>>(s2, sd3w, sd3b, out + 1420800);
}

// Round 4
// 6951.617 us; speedup vs baseline: 3.9180x; 1.2199x over previous
//
#include <hip/hip_runtime.h>
#include <hip/hip_bf16.h>
#include <math.h>

// ---------------------------------------------------------------------------
// DeepMonocularModel — r4: dg1/dg2 + score-head GEMMs moved to bf16 MFMA;
// conv2 epilogue fuses padded-bf16 feats emit + token(+pos) build.
// ---------------------------------------------------------------------------

#define NB   32
#define ND   768
#define NTOK 1024
#define NKH  8
#define NHD  96
#define NL   4
#define NMLP 3072
#define NK   50
#define NT   30

typedef short  s8v __attribute__((ext_vector_type(8)));
typedef float  f4v __attribute__((ext_vector_type(4)));

__device__ __forceinline__ float gelu_f(float x) {
    return 0.5f * x * (1.0f + erff(x * 0.70710678118654752f));
}
__device__ __forceinline__ float softplus_f(float x) {
    return x > 0.f ? x + log1pf(expf(-x)) : log1pf(expf(x));
}
__device__ __forceinline__ void gld_lds16(const void* g, void* l) {
    __builtin_amdgcn_global_load_lds(
        (const __attribute__((address_space(1))) void*)g,
        (__attribute__((address_space(3))) void*)l, 16, 0, 0);
}

// ---------------------------------------------------------------------------
// bf16 MFMA GEMM, 128x128 tile. C = act(A_view @ Bt^T + bias)
// AMODE 0: A plain bf16 [*][K] (alloc must cover grid rows)
// AMODE 1: A padded NHWC bf16 [b][34][34][768], 3x3 conv, K = tap*768+ci
// OUT 0: fp32 Cf[m*N+n]
// OUT 1: bf16 padded-768 NHWC (conv1 intermediate)
// OUT 2: bf16 plain Cb[m*N+n]
// OUT 3: conv2 special — bf16 padded-768 NHWC (feats) + bf16 tokens w/ +pos
// Stores guarded by m<M.
// ---------------------------------------------------------------------------
template<int AMODE, int ACT, int OUT>
__global__ __launch_bounds__(256) void mfma_gemm_k(
    const __hip_bfloat16* __restrict__ A,
    const __hip_bfloat16* __restrict__ Bt,
    const float* __restrict__ bias,
    float* __restrict__ Cf,
    __hip_bfloat16* __restrict__ Cb,
    __hip_bfloat16* __restrict__ Cpad,
    const float* __restrict__ pos,
    int M, int N, int K)
{
    __shared__ __hip_bfloat16 As[128 * 32];
    __shared__ __hip_bfloat16 Bs[128 * 32];
    const int tid  = threadIdx.x;
    const int lane = tid & 63;
    const int wave = tid >> 6;
    const int wm = wave >> 1, wn = wave & 1;
    const int bm = blockIdx.y * 128, bn = blockIdx.x * 128;
    const int r0 = tid >> 2;
    const int kb = (tid & 3) * 8;

    f4v acc[4][4];
#pragma unroll
    for (int i = 0; i < 4; i++)
#pragma unroll
        for (int j = 0; j < 4; j++) acc[i][j] = (f4v)0.f;

    int rr = 0, kin = 0;
    for (int k0 = 0; k0 < K; k0 += 32) {
#pragma unroll
        for (int c = 0; c < 2; c++) {
            const int row = r0 + c * 64;
            const __hip_bfloat16* ga;
            if constexpr (AMODE == 0) {
                ga = A + (size_t)(bm + row) * K + k0 + kb;
            } else {
                int gm = bm + row;
                int b = gm >> 10, y = (gm >> 5) & 31, x = gm & 31;
                int dy = rr / 3, dx = rr - dy * 3;
                ga = A + ((((size_t)b * 34 + y + dy) * 34 + (x + dx)) * 768 + kin + kb);
            }
            gld_lds16(ga, &As[row * 32 + kb]);
        }
#pragma unroll
        for (int c = 0; c < 2; c++) {
            const int row = r0 + c * 64;
            gld_lds16(Bt + (size_t)(bn + row) * K + k0 + kb, &Bs[row * 32 + kb]);
        }
        __syncthreads();
        const int koff = (lane >> 4) * 8;
        s8v af[4], bfv[4];
#pragma unroll
        for (int i = 0; i < 4; i++)
            af[i] = *(const s8v*)(&As[(wm * 64 + i * 16 + (lane & 15)) * 32 + koff]);
#pragma unroll
        for (int j = 0; j < 4; j++)
            bfv[j] = *(const s8v*)(&Bs[(wn * 64 + j * 16 + (lane & 15)) * 32 + koff]);
#pragma unroll
        for (int i = 0; i < 4; i++)
#pragma unroll
            for (int j = 0; j < 4; j++)
                acc[i][j] = __builtin_amdgcn_mfma_f32_16x16x32_bf16(af[i], bfv[j], acc[i][j], 0, 0, 0);
        __syncthreads();
        if constexpr (AMODE == 1) { kin += 32; if (kin == 768) { kin = 0; rr++; } }
    }
#pragma unroll
    for (int i = 0; i < 4; i++) {
        const int mbase = bm + wm * 64 + i * 16 + ((lane >> 4) << 2);
#pragma unroll
        for (int j = 0; j < 4; j++) {
            const int n = bn + wn * 64 + j * 16 + (lane & 15);
            const float bs = bias[n];
#pragma unroll
            for (int g = 0; g < 4; g++) {
                const int m = mbase + g;
                if (m >= M) continue;
                float v = acc[i][j][g] + bs;
                if constexpr (ACT == 1) v = gelu_f(v);
                if constexpr (OUT == 0) {
                    Cf[(size_t)m * N + n] = v;
                } else if constexpr (OUT == 1) {
                    int b = m >> 10, y = (m >> 5) & 31, x = m & 31;
                    Cpad[(((size_t)b * 34 + y + 1) * 34 + (x + 1)) * 768 + n] =
                        __float2bfloat16(v);
                } else if constexpr (OUT == 2) {
                    Cb[(size_t)m * N + n] = __float2bfloat16(v);
                } else {
                    int b = m >> 10, y = (m >> 5) & 31, x = m & 31;
                    Cpad[(((size_t)b * 34 + y + 1) * 34 + (x + 1)) * 768 + n] =
                        __float2bfloat16(v);
                    Cb[(size_t)m * 768 + n] =
                        __float2bfloat16(v + pos[(size_t)(m & 1023) * 768 + n]);
                }
            }
        }
    }
}

// ---------------------------------------------------------------------------
// dg1: 3x3 conv 768->64, gelu, in/out padded bf16. Tile 128(M)x64(N).
// A: [32][34][34][768]; Bt: [64][6912]; Dpad: [32][34][34][64]
// ---------------------------------------------------------------------------
__global__ __launch_bounds__(256) void mfma_dg1_k(
    const __hip_bfloat16* __restrict__ A,
    const __hip_bfloat16* __restrict__ Bt,
    const float* __restrict__ bias,
    __hip_bfloat16* __restrict__ Dpad)
{
    __shared__ __hip_bfloat16 As[128 * 32];
    __shared__ __hip_bfloat16 Bs[64 * 32];
    const int tid = threadIdx.x, lane = tid & 63, wave = tid >> 6;
    const int wm = wave >> 1, wn = wave & 1;
    const int bm = blockIdx.x * 128;
    const int r0 = tid >> 2, kb = (tid & 3) * 8;
    f4v acc[4][2];
#pragma unroll
    for (int i = 0; i < 4; i++)
#pragma unroll
        for (int j = 0; j < 2; j++) acc[i][j] = (f4v)0.f;

    int rr = 0, kin = 0;
    for (int k0 = 0; k0 < 6912; k0 += 32) {
#pragma unroll
        for (int c = 0; c < 2; c++) {
            const int row = r0 + c * 64;
            int gm = bm + row;
            int b = gm >> 10, y = (gm >> 5) & 31, x = gm & 31;
            int dy = rr / 3, dx = rr - dy * 3;
            gld_lds16(A + ((((size_t)b * 34 + y + dy) * 34 + (x + dx)) * 768 + kin + kb),
                      &As[row * 32 + kb]);
        }
        gld_lds16(Bt + (size_t)r0 * 6912 + k0 + kb, &Bs[r0 * 32 + kb]);
        __syncthreads();
        const int koff = (lane >> 4) * 8;
        s8v af[4], bfv[2];
#pragma unroll
        for (int i = 0; i < 4; i++)
            af[i] = *(const s8v*)(&As[(wm * 64 + i * 16 + (lane & 15)) * 32 + koff]);
#pragma unroll
        for (int j = 0; j < 2; j++)
            bfv[j] = *(const s8v*)(&Bs[(wn * 32 + j * 16 + (lane & 15)) * 32 + koff]);
#pragma unroll
        for (int i = 0; i < 4; i++)
#pragma unroll
            for (int j = 0; j < 2; j++)
                acc[i][j] = __builtin_amdgcn_mfma_f32_16x16x32_bf16(af[i], bfv[j], acc[i][j], 0, 0, 0);
        __syncthreads();
        kin += 32; if (kin == 768) { kin = 0; rr++; }
    }
#pragma unroll
    for (int i = 0; i < 4; i++) {
        const int mbase = bm + wm * 64 + i * 16 + ((lane >> 4) << 2);
#pragma unroll
        for (int j = 0; j < 2; j++) {
            const int n = wn * 32 + j * 16 + (lane & 15);
            const float bs = bias[n];
#pragma unroll
            for (int g = 0; g < 4; g++) {
                const int m = mbase + g;
                float v = gelu_f(acc[i][j][g] + bs);
                int b = m >> 10, y = (m >> 5) & 31, x = m & 31;
                Dpad[(((size_t)b * 34 + y + 1) * 34 + (x + 1)) * 64 + n] =
                    __float2bfloat16(v);
            }
        }
    }
}

// ---------------------------------------------------------------------------
// dg2: up2 + 3x3 conv 64->32, gelu. Tile 128(M)x32(N). Output 64x64/batch.
// A: d1pad [32][34][34][64]; Bt: [32][576]; D: fp32 [131072][32]
// upsample fold: iy_pad = (y+dy+1)>>1 (verified against pad border)
// ---------------------------------------------------------------------------
__global__ __launch_bounds__(256) void mfma_dg2_k(
    const __hip_bfloat16* __restrict__ A,
    const __hip_bfloat16* __restrict__ Bt,
    const float* __restrict__ bias,
    float* __restrict__ D)
{
    __shared__ __hip_bfloat16 As[128 * 32];
    __shared__ __hip_bfloat16 Bs[32 * 32];
    const int tid = threadIdx.x, lane = tid & 63, wave = tid >> 6;
    const int bm = blockIdx.x * 128;
    const int r0 = tid >> 2, kb = (tid & 3) * 8;
    f4v acc[2][2];
#pragma unroll
    for (int i = 0; i < 2; i++)
#pragma unroll
        for (int j = 0; j < 2; j++) acc[i][j] = (f4v)0.f;

    int rr = 0, kin = 0;
    for (int k0 = 0; k0 < 576; k0 += 32) {
#pragma unroll
        for (int c = 0; c < 2; c++) {
            const int row = r0 + c * 64;
            int gm = bm + row;
            int b = gm >> 12, y = (gm >> 6) & 63, x = gm & 63;
            int dy = rr / 3, dx = rr - dy * 3;
            int iy = (y + dy + 1) >> 1, ix = (x + dx + 1) >> 1;
            gld_lds16(A + (((size_t)b * 34 + iy) * 34 + ix) * 64 + kin + kb,
                      &As[row * 32 + kb]);
        }
        if (tid < 128)
            gld_lds16(Bt + (size_t)r0 * 576 + k0 + kb, &Bs[r0 * 32 + kb]);
        __syncthreads();
        const int koff = (lane >> 4) * 8;
        s8v af[2], bfv[2];
#pragma unroll
        for (int i = 0; i < 2; i++)
            af[i] = *(const s8v*)(&As[(wave * 32 + i * 16 + (lane & 15)) * 32 + koff]);
#pragma unroll
        for (int j = 0; j < 2; j++)
            bfv[j] = *(const s8v*)(&Bs[(j * 16 + (lane & 15)) * 32 + koff]);
#pragma unroll
        for (int i = 0; i < 2; i++)
#pragma unroll
            for (int j = 0; j < 2; j++)
                acc[i][j] = __builtin_amdgcn_mfma_f32_16x16x32_bf16(af[i], bfv[j], acc[i][j], 0, 0, 0);
        __syncthreads();
        kin += 32; if (kin == 64) { kin = 0; rr++; }
    }
#pragma unroll
    for (int i = 0; i < 2; i++) {
        const int mbase = bm + wave * 32 + i * 16 + ((lane >> 4) << 2);
#pragma unroll
        for (int j = 0; j < 2; j++) {
            const int n = j * 16 + (lane & 15);
            const float bs = bias[n];
#pragma unroll
            for (int g = 0; g < 4; g++) {
                const int m = mbase + g;
                D[(size_t)m * 32 + n] = gelu_f(acc[i][j][g] + bs);
            }
        }
    }
}

// NCHW fp32 -> padded NHWC bf16 interior
__global__ void nchw2pad_bf_k(const float* __restrict__ src, __hip_bfloat16* __restrict__ dst)
{
    __shared__ float tile[32][33];
    int b = blockIdx.z, n0 = blockIdx.y * 32, c0 = blockIdx.x * 32;
    int tx = threadIdx.x, ty = threadIdx.y;
#pragma unroll
    for (int i = ty; i < 32; i += 8)
        tile[i][tx] = src[((size_t)b * ND + c0 + i) * NTOK + n0 + tx];
    __syncthreads();
#pragma unroll
    for (int i = ty; i < 32; i += 8) {
        int n = n0 + i, y = n >> 5, x = n & 31;
        dst[(((size_t)b * 34 + y + 1) * 34 + (x + 1)) * 768 + c0 + tx] =
            __float2bfloat16(tile[tx][i]);
    }
}

// zero borders of two padded-768 bf16 buffers
__global__ void pad_border_k(__hip_bfloat16* __restrict__ p1, __hip_bfloat16* __restrict__ p2)
{
    int idx = blockIdx.x * 256 + threadIdx.x;
    if (idx >= 32 * 132 * 192) return;
    int c4 = idx % 192;
    int cell = (idx / 192) % 132;
    int b = idx / (192 * 132);
    int yy, xx;
    if      (cell < 34)  { yy = 0;  xx = cell; }
    else if (cell < 68)  { yy = 33; xx = cell - 34; }
    else if (cell < 100) { yy = cell - 68 + 1;  xx = 0; }
    else                 { yy = cell - 100 + 1; xx = 33; }
    size_t o = (((size_t)b * 34 + yy) * 34 + xx) * 768 + c4 * 4;
    *reinterpret_cast<uint2*>(p1 + o) = make_uint2(0u, 0u);
    *reinterpret_cast<uint2*>(p2 + o) = make_uint2(0u, 0u);
}

// zero border of padded-64 bf16 buffer
__global__ void pad_border64_k(__hip_bfloat16* __restrict__ p)
{
    int idx = blockIdx.x * 256 + threadIdx.x;
    if (idx >= 32 * 132 * 16) return;
    int c4 = idx % 16;
    int cell = (idx / 16) % 132;
    int b = idx / (16 * 132);
    int yy, xx;
    if      (cell < 34)  { yy = 0;  xx = cell; }
    else if (cell < 68)  { yy = 33; xx = cell - 34; }
    else if (cell < 100) { yy = cell - 68 + 1;  xx = 0; }
    else                 { yy = cell - 100 + 1; xx = 33; }
    size_t o = (((size_t)b * 34 + yy) * 34 + xx) * 64 + c4 * 4;
    *reinterpret_cast<uint2*>(p + o) = make_uint2(0u, 0u);
}

// conv weight OIHW fp32 -> bf16 [n][tap*Cin+ci]
__global__ void convw_bf_k(const float* __restrict__ w, __hip_bfloat16* __restrict__ wT,
                           int Cout, int Cin)
{
    int idx = blockIdx.x * 256 + threadIdx.x;
    if (idx >= Cout * Cin * 9) return;
    int n = idx / (Cin * 9), k = idx - n * (Cin * 9);
    int r = k / Cin, ci = k - r * Cin;
    wT[idx] = __float2bfloat16(w[((size_t)n * Cin + ci) * 9 + r]);
}

// [K][N] fp32 -> [N][K] bf16, tiled transpose (K,N multiples of 32)
__global__ void wt_bf_k(const float* __restrict__ w, __hip_bfloat16* __restrict__ wT,
                        int K, int N)
{
    __shared__ float t[32][33];
    int k0 = blockIdx.y * 32, n0 = blockIdx.x * 32;
    int tx = threadIdx.x, ty = threadIdx.y;
#pragma unroll
    for (int i = ty; i < 32; i += 8)
        t[i][tx] = w[(size_t)(k0 + i) * N + n0 + tx];
    __syncthreads();
#pragma unroll
    for (int i = ty; i < 32; i += 8)
        wT[(size_t)(n0 + i) * K + k0 + tx] = __float2bfloat16(t[tx][i]);
}

// fp32 -> bf16 flat convert
__global__ void f2bf_k(const float* __restrict__ s, __hip_bfloat16* __restrict__ d, int n)
{
    int i = blockIdx.x * 256 + threadIdx.x;
    if (i < n) d[i] = __float2bfloat16(s[i]);
}

// catbf[r][0:768] = bf16(q[r/50]); catbf[r][768:1536] = tfbbf[r]; rows>=1600 -> 0
__global__ void cat_bf_k(const float* __restrict__ q, const __hip_bfloat16* __restrict__ tf,
                         __hip_bfloat16* __restrict__ cat)
{
    int idx = blockIdx.x * 256 + threadIdx.x;
    if (idx >= 1664 * 1536) return;
    int r = idx / 1536, c = idx - r * 1536;
    __hip_bfloat16 v;
    if (r < 1600)
        v = (c < 768) ? __float2bfloat16(q[(size_t)(r / 50) * 768 + c])
                      : tf[(size_t)r * 768 + (c - 768)];
    else v = __float2bfloat16(0.f);
    cat[idx] = v;
}

// ---------------------------------------------------------------------------
// fp32 tiled GEMM — small GEMMs only (AMODE 0)
// ---------------------------------------------------------------------------
template<int ACT, int RES>
__global__ __launch_bounds__(256) void gemm_k(
    const float* __restrict__ A, const float* __restrict__ Bw,
    const float* __restrict__ bias, const float* __restrict__ res,
    float* __restrict__ C, int M, int N, int K)
{
    __shared__ float As[16][68];
    __shared__ float Bs[16][68];
    const int tx = threadIdx.x, ty = threadIdx.y;
    const int tid = ty * 16 + tx;
    const int bm = blockIdx.y * 64, bn = blockIdx.x * 64;
    float acc[4][4] = {};

    for (int k0 = 0; k0 < K; k0 += 16) {
#pragma unroll
        for (int i = 0; i < 4; i++) {
            int idx = i * 256 + tid;
            int ml = idx >> 4, kl = idx & 15;
            int m = bm + ml, k = k0 + kl;
            As[kl][ml] = (m < M && k < K) ? A[(size_t)m * K + k] : 0.f;
        }
#pragma unroll
        for (int i = 0; i < 4; i++) {
            int idx = i * 256 + tid;
            int nl = idx & 63, kl = idx >> 6;
            int k = k0 + kl, n = bn + nl;
            Bs[kl][nl] = (k < K && n < N) ? Bw[(size_t)k * N + n] : 0.f;
        }
        __syncthreads();
#pragma unroll
        for (int kk = 0; kk < 16; kk++) {
            const float4 av = *reinterpret_cast<const float4*>(&As[kk][ty * 4]);
            const float4 bv = *reinterpret_cast<const float4*>(&Bs[kk][tx * 4]);
            const float a4[4] = {av.x, av.y, av.z, av.w};
            const float b4[4] = {bv.x, bv.y, bv.z, bv.w};
#pragma unroll
            for (int i = 0; i < 4; i++)
#pragma unroll
                for (int j = 0; j < 4; j++)
                    acc[i][j] = fmaf(a4[i], b4[j], acc[i][j]);
        }
        __syncthreads();
    }
#pragma unroll
    for (int i = 0; i < 4; i++) {
        int m = bm + ty * 4 + i;
        if (m >= M) continue;
#pragma unroll
        for (int j = 0; j < 4; j++) {
            int n = bn + tx * 4 + j;
            if (n >= N) continue;
            float v = acc[i][j] + bias[n];
            if constexpr (ACT == 1) v = gelu_f(v);
            if constexpr (RES == 1) v += res[(size_t)m * N + n];
            C[(size_t)m * N + n] = v;
        }
    }
}

__global__ void depth_k(const float* __restrict__ d2,
                        const float* __restrict__ w3, const float* __restrict__ b3,
                        float* __restrict__ out)
{
    int idx = blockIdx.x * 256 + threadIdx.x;
    if (idx >= NB * 128 * 128) return;
    int b = idx >> 14;
    int rem = idx & 16383;
    int y = rem >> 7, x = rem & 127;
    const float* base = d2 + (((size_t)b * 64 + (y >> 1)) * 64 + (x >> 1)) * 32;
    float acc = b3[0];
#pragma unroll
    for (int ci = 0; ci < 32; ci++) acc = fmaf(base[ci], w3[ci], acc);
    out[idx] = softplus_f(acc);
}

__global__ void ln_k(const float* __restrict__ x, const float* __restrict__ g,
                     const float* __restrict__ bb, float* __restrict__ y)
{
    int r = blockIdx.x, t = threadIdx.x;
    __shared__ float red[256];
    float v0 = x[(size_t)r * ND + t];
    float v1 = x[(size_t)r * ND + 256 + t];
    float v2 = x[(size_t)r * ND + 512 + t];
    red[t] = v0 + v1 + v2;
    __syncthreads();
    for (int s = 128; s > 0; s >>= 1) { if (t < s) red[t] += red[t + s]; __syncthreads(); }
    float mean = red[0] * (1.0f / ND);
    __syncthreads();
    float d0 = v0 - mean, d1 = v1 - mean, d2 = v2 - mean;
    red[t] = d0 * d0 + d1 * d1 + d2 * d2;
    __syncthreads();
    for (int s = 128; s > 0; s >>= 1) { if (t < s) red[t] += red[t + s]; __syncthreads(); }
    float inv = 1.0f / sqrtf(red[0] * (1.0f / ND) + 1e-5f);
    y[(size_t)r * ND + t]       = d0 * inv * g[t]       + bb[t];
    y[(size_t)r * ND + 256 + t] = d1 * inv * g[256 + t] + bb[256 + t];
    y[(size_t)r * ND + 512 + t] = d2 * inv * g[512 + t] + bb[512 + t];
}

__global__ void attn_scores_k(const float* __restrict__ Qp,
                              const float* __restrict__ Kb,
                              float* __restrict__ att)
{
    int bh = blockIdx.x;
    int b = bh >> 3, h = bh & 7;
    __shared__ float qs[NHD];
    __shared__ float sc[NTOK];
    __shared__ float red[256];
    int t = threadIdx.x;
    if (t < NHD) qs[t] = Qp[(size_t)b * ND + h * NHD + t];
    __syncthreads();
    const float scale = 0.1020620726159658f;
    for (int k = t; k < NTOK; k += 256) {
        const float* kr = Kb + ((size_t)b * NTOK + k) * ND + h * NHD;
        float s = 0.f;
#pragma unroll 8
        for (int d = 0; d < NHD; d++) s = fmaf(qs[d], kr[d], s);
        sc[k] = s * scale;
    }
    __syncthreads();
    float m = -1e30f;
    for (int k = t; k < NTOK; k += 256) m = fmaxf(m, sc[k]);
    red[t] = m; __syncthreads();
    for (int s = 128; s > 0; s >>= 1) { if (t < s) red[t] = fmaxf(red[t], red[t + s]); __syncthreads(); }
    m = red[0]; __syncthreads();
    float sum = 0.f;
    for (int k = t; k < NTOK; k += 256) { float e = expf(sc[k] - m); sc[k] = e; sum += e; }
    red[t] = sum; __syncthreads();
    for (int s = 128; s > 0; s >>= 1) { if (t < s) red[t] += red[t + s]; __syncthreads(); }
    float inv = 1.0f / red[0];
    for (int k = t; k < NTOK; k += 256) att[(size_t)bh * NTOK + k] = sc[k] * inv;
}

__global__ void attn_av_k(const float* __restrict__ att,
                          const float* __restrict__ Vb,
                          float* __restrict__ o)
{
    int bh = blockIdx.x;
    int b = bh >> 3, h = bh & 7;
    __shared__ float p[NTOK];
    int t = threadIdx.x;
    for (int k = t; k < NTOK; k += 128) p[k] = att[(size_t)bh * NTOK + k];
    __syncthreads();
    if (t < NHD) {
        const float* vp = Vb + (size_t)b * NTOK * ND + h * NHD + t;
        float acc = 0.f;
        for (int k = 0; k < NTOK; k++) acc = fmaf(p[k], vp[(size_t)k * ND], acc);
        o[(size_t)b * ND + h * NHD + t] = acc;
    }
}

__global__ void build_qa_k(const int* __restrict__ intent,
                           const float* __restrict__ past,
                           float* __restrict__ qA)
{
    int idx = blockIdx.x * 256 + threadIdx.x;
    if (idx >= NB * 99) return;
    int b = idx / 99, j = idx - b * 99;
    float v;
    if (j < 3) v = (intent[b] - 1 == j) ? 1.f : 0.f;
    else       v = past[b * 96 + (j - 3)];
    qA[idx] = v;
}

__global__ void integrate_k(const float* __restrict__ cp,
                            const float* __restrict__ past,
                            float* __restrict__ out)
{
    int idx = blockIdx.x * 256 + threadIdx.x;
    if (idx >= NB * NK) return;
    int b = idx / NK, k = idx - b * NK;
    const float* pl = past + b * 96 + 90;
    float x = pl[0], y = pl[1], vx = pl[2], vy = pl[3];
    float s  = sqrtf(vx * vx + vy * vy + 1e-6f);
    float hd = atan2f(vy, vx);
    const float* cpk = cp + (size_t)b * 3000 + k * 60;
    float* o0 = out +        (size_t)b * 3000 + k * 60;
    float* o1 = out + 96000 + (size_t)b * 3000 + k * 60;
    float* c5 = out + 1946688 + (size_t)b * 3000 + k * 60;
    float* c6 = out + 2042688 + (size_t)b * 3000 + k * 60;
    const float DT = 0.25f;
    for (int t = 0; t < NT; t++) {
        float a = tanhf(cpk[t * 2 + 0]) * 8.0f;
        float w = tanhf(cpk[t * 2 + 1]) * 1.0f;
        x += s * cosf(hd) * DT;
        y += s * sinf(hd) * DT;
        o0[t * 2 + 0] = x; o0[t * 2 + 1] = y;
        o1[t * 2 + 0] = x; o1[t * 2 + 1] = y;
        c5[t * 2 + 0] = a; c5[t * 2 + 1] = w;
        c6[t * 2 + 0] = a; c6[t * 2 + 1] = w;
        hd += w * DT;
        s = fmaxf(s + a * DT, 0.f);
    }
}

__global__ void qscore_k(const float* __restrict__ q, float* __restrict__ out2)
{
    int idx = blockIdx.x * 256 + threadIdx.x;
    if (idx >= NB * NK * ND) return;
    int r = idx / ND, d = idx - r * ND;
    int b = r / NK;
    out2[idx] = q[(size_t)b * ND + d];
}

__global__ void score_k(const float* __restrict__ sc2, const float* __restrict__ w,
                        const float* __restrict__ bias, float* __restrict__ out)
{
    int r = blockIdx.x * 4 + (threadIdx.x >> 6);
    int lane = threadIdx.x & 63;
    if (r >= NB * NK) return;
    float acc = 0.f;
    for (int d = lane; d < ND; d += 64) acc = fmaf(sc2[(size_t)r * ND + d], w[d], acc);
    for (int off = 32; off > 0; off >>= 1) acc += __shfl_down(acc, off, 64);
    if (lane == 0) out[r] = acc + bias[0];
}

// ---------------------------------------------------------------------------
static inline void gemm(hipStream_t st, int act, int hasres,
                        const float* A, const float* Bw, const float* bias,
                        const float* res, float* C, int M, int N, int K)
{
    dim3 blk(16, 16), grd((N + 63) / 64, (M + 63) / 64);
    if      (act == 0 && !hasres) gemm_k<0, 0><<<grd, blk, 0, st>>>(A, Bw, bias, res, C, M, N, K);
    else if (act == 0 &&  hasres) gemm_k<0, 1><<<grd, blk, 0, st>>>(A, Bw, bias, res, C, M, N, K);
    else                          gemm_k<1, 0><<<grd, blk, 0, st>>>(A, Bw, bias, res, C, M, N, K);
}

extern "C" void kernel_launch(void* const* d_in, const int* in_sizes, int n_in,
                              void* d_out, int out_size, void* d_ws, size_t ws_size,
                              hipStream_t stream)
{
    const float* feats_vit = (const float*)d_in[0];
    const float* past      = (const float*)d_in[1];
    const int*   intent    = (const int*)  d_in[2];
    const float* qi_w   = (const float*)d_in[3];
    const float* qi_b   = (const float*)d_in[4];
    const float* va1_w  = (const float*)d_in[5];
    const float* va1_b  = (const float*)d_in[6];
    const float* va2_w  = (const float*)d_in[7];
    const float* va2_b  = (const float*)d_in[8];
    const float* pos    = (const float*)d_in[9];
    const float* ln1_g  = (const float*)d_in[10];
    const float* ln1_b  = (const float*)d_in[11];
    const float* wq     = (const float*)d_in[12];
    const float* bq     = (const float*)d_in[13];
    const float* wk     = (const float*)d_in[14];
    const float* bk     = (const float*)d_in[15];
    const float* wv     = (const float*)d_in[16];
    const float* bv     = (const float*)d_in[17];
    const float* wo     = (const float*)d_in[18];
    const float* bo     = (const float*)d_in[19];
    const float* ln2_g  = (const float*)d_in[20];
    const float* ln2_b  = (const float*)d_in[21];
    const float* m1w    = (const float*)d_in[22];
    const float* m1b    = (const float*)d_in[23];
    const float* m2w    = (const float*)d_in[24];
    const float* m2b    = (const float*)d_in[25];
    const float* dg1w   = (const float*)d_in[26];
    const float* dg1b   = (const float*)d_in[27];
    const float* dg2w   = (const float*)d_in[28];
    const float* dg2b   = (const float*)d_in[29];
    const float* dg3w   = (const float*)d_in[30];
    const float* dg3b   = (const float*)d_in[31];
    const float* td1w   = (const float*)d_in[32];
    const float* td1b   = (const float*)d_in[33];
    const float* td2w   = (const float*)d_in[34];
    const float* td2b   = (const float*)d_in[35];
    const float* td3w   = (const float*)d_in[36];
    const float* td3b   = (const float*)d_in[37];
    const float* tf1w   = (const float*)d_in[38];
    const float* tf1b   = (const float*)d_in[39];
    const float* tf2w   = (const float*)d_in[40];
    const float* tf2b   = (const float*)d_in[41];
    const float* sd1w   = (const float*)d_in[42];
    const float* sd1b   = (const float*)d_in[43];
    const float* sd2w   = (const float*)d_in[44];
    const float* sd2b   = (const float*)d_in[45];
    const float* sd3w   = (const float*)d_in[46];
    const float* sd3b   = (const float*)d_in[47];

    float* out = (float*)d_out;
    float* ws  = (float*)d_ws;

    // workspace layout (float units)
    size_t off = 0;
    float* bufB    = ws + off; off += (size_t)NB * ND * NTOK;   // K/V fp32; early: xpad2 alias
    float* xpad_f  = ws + off; off += 14201856;                 // input padded bf16 / tokens bf16
    float* c1pad_f = ws + off; off += 14201856;                 // conv1 out padded bf16 / late: score bufs + d1pad
    float* wTc_f   = ws + off; off += 2654208;                  // conv weights bf16 [768][6912]
    float* wkT_f   = ws + off; off += 294912;
    float* wvT_f   = ws + off; off += 294912;
    float* dg1wT_f = ws + off; off += 221184;                   // [64][6912] bf16
    float* dg2wT_f = ws + off; off += 9216;                     // [32][576]  bf16
    float* tf2wT_f = ws + off; off += 294912;
    float* sd1wT_f = ws + off; off += 589824;                   // [768][1536] bf16
    float* sd2wT_f = ws + off; off += 294912;
    float* d2      = ws + off; off += (size_t)NB * 4096 * 32;
    float* attb    = ws + off; off += (size_t)NB * NKH * NTOK;
    float* q       = ws + off; off += NB * ND;
    float* qn      = ws + off; off += NB * ND;
    float* Qp      = ws + off; off += NB * ND;
    float* ob      = ws + off; off += NB * ND;
    float* hm      = ws + off; off += NB * NMLP;
    float* qA      = ws + off; off += NB * 128;
    float* h1      = ws + off; off += NB * ND;
    float* h2      = ws + off; off += NB * ND;
    float* cp      = ws + off; off += NB * 3000;
    // bf16 aliases
    __hip_bfloat16* xpad   = (__hip_bfloat16*)xpad_f;
    __hip_bfloat16* c1pad  = (__hip_bfloat16*)c1pad_f;
    __hip_bfloat16* xpad2  = (__hip_bfloat16*)bufB;             // feats padded bf16 (pre-transformer only)
    __hip_bfloat16* tokbf  = (__hip_bfloat16*)xpad_f;           // tokens bf16 (after conv1 frees xpad)
    __hip_bfloat16* wTc    = (__hip_bfloat16*)wTc_f;
    __hip_bfloat16* wkT    = (__hip_bfloat16*)wkT_f;
    __hip_bfloat16* wvT    = (__hip_bfloat16*)wvT_f;
    __hip_bfloat16* dg1wT  = (__hip_bfloat16*)dg1wT_f;
    __hip_bfloat16* dg2wT  = (__hip_bfloat16*)dg2wT_f;
    __hip_bfloat16* tf2wT  = (__hip_bfloat16*)tf2wT_f;
    __hip_bfloat16* sd1wT  = (__hip_bfloat16*)sd1wT_f;
    __hip_bfloat16* sd2wT  = (__hip_bfloat16*)sd2wT_f;
    // score-head buffers carved from c1pad region (free after conv2)
    float* tfa            = c1pad_f;                            // 1600x768 fp32
    __hip_bfloat16* tfabf = (__hip_bfloat16*)(c1pad_f + 1228800);  // 1664x768
    __hip_bfloat16* tfbbf = (__hip_bfloat16*)(c1pad_f + 1867776);  // 1664x768
    __hip_bfloat16* catbf = (__hip_bfloat16*)(c1pad_f + 2506752);  // 1664x1536
    __hip_bfloat16* s1bf  = (__hip_bfloat16*)(c1pad_f + 3784704);  // 1664x768
    float* s2             = c1pad_f + 4423680;                     // 1664x768 fp32
    __hip_bfloat16* d1pad = (__hip_bfloat16*)(c1pad_f + 8000000);  // [32][34][34][64]
    (void)ws_size; (void)n_in; (void)in_sizes; (void)out_size;

    const int M_PIX = NB * 1024;

    // ---- prep: borders, input transpose, conv weights ----
    pad_border_k<<<(32 * 132 * 192 + 255) / 256, 256, 0, stream>>>(xpad, c1pad);
    pad_border_k<<<(32 * 132 * 192 + 255) / 256, 256, 0, stream>>>(xpad2, xpad2);
    pad_border64_k<<<(32 * 132 * 16 + 255) / 256, 256, 0, stream>>>(d1pad);
    nchw2pad_bf_k<<<dim3(ND / 32, NTOK / 32, NB), dim3(32, 8), 0, stream>>>(feats_vit, xpad);
    convw_bf_k<<<(768 * 768 * 9 + 255) / 256, 256, 0, stream>>>(va1_w, wTc, 768, 768);

    // ---- conv1 (gelu -> padded bf16) ----
    mfma_gemm_k<1, 1, 1><<<dim3(6, 256), 256, 0, stream>>>(
        xpad, wTc, va1_b, nullptr, nullptr, c1pad, nullptr, M_PIX, ND, ND * 9);
    convw_bf_k<<<(768 * 768 * 9 + 255) / 256, 256, 0, stream>>>(va2_w, wTc, 768, 768);
    // ---- conv2 (-> padded bf16 feats + bf16 tokens with +pos) ----
    mfma_gemm_k<1, 0, 3><<<dim3(6, 256), 256, 0, stream>>>(
        c1pad, wTc, va2_b, nullptr, tokbf, xpad2, pos, M_PIX, ND, ND * 9);

    // ---- depth branch (bf16 MFMA) ----
    convw_bf_k<<<(64 * 768 * 9 + 255) / 256, 256, 0, stream>>>(dg1w, dg1wT, 64, 768);
    mfma_dg1_k<<<256, 256, 0, stream>>>(xpad2, dg1wT, dg1b, d1pad);
    convw_bf_k<<<(32 * 64 * 9 + 255) / 256, 256, 0, stream>>>(dg2w, dg2wT, 32, 64);
    mfma_dg2_k<<<1024, 256, 0, stream>>>(d1pad, dg2wT, dg2b, d2);
    depth_k<<<(NB * 16384 + 255) / 256, 256, 0, stream>>>(d2, dg3w, dg3b, out + 1422400);

    // ---- q init ----
    build_qa_k<<<(NB * 99 + 255) / 256, 256, 0, stream>>>(intent, past, qA);
    gemm(stream, 0, 0, qA, qi_w, qi_b, nullptr, q, NB, ND, 99);

    // ---- transformer layers ----
    for (int i = 0; i < NL; i++) {
        const size_t W = (size_t)i * ND * ND;
        ln_k<<<NB, 256, 0, stream>>>(q, ln1_g + i * ND, ln1_b + i * ND, qn);
        gemm(stream, 0, 0, qn, wq + W, bq + i * ND, nullptr, Qp, NB, ND, ND);
        wt_bf_k<<<dim3(24, 24), dim3(32, 8), 0, stream>>>(wk + W, wkT, 768, 768);
        mfma_gemm_k<0, 0, 0><<<dim3(6, 256), 256, 0, stream>>>(
            tokbf, wkT, bk + i * ND, bufB, nullptr, nullptr, nullptr, M_PIX, ND, ND);
        attn_scores_k<<<NB * NKH, 256, 0, stream>>>(Qp, bufB, attb);
        wt_bf_k<<<dim3(24, 24), dim3(32, 8), 0, stream>>>(wv + W, wvT, 768, 768);
        mfma_gemm_k<0, 0, 0><<<dim3(6, 256), 256, 0, stream>>>(
            tokbf, wvT, bv + i * ND, bufB, nullptr, nullptr, nullptr, M_PIX, ND, ND);
        attn_av_k<<<NB * NKH, 128, 0, stream>>>(attb, bufB, ob);
        gemm(stream, 0, 1, ob, wo + W, bo + i * ND, q, q, NB, ND, ND);
        ln_k<<<NB, 256, 0, stream>>>(q, ln2_g + i * ND, ln2_b + i * ND, qn);
        gemm(stream, 1, 0, qn, m1w + (size_t)i * ND * NMLP, m1b + i * NMLP,
             nullptr, hm, NB, NMLP, ND);
        gemm(stream, 0, 1, hm, m2w + (size_t)i * NMLP * ND, m2b + i * ND,
             q, q, NB, ND, NMLP);
    }

    // ---- trajectory decoder ----
    gemm(stream, 1, 0, q,  td1w, td1b, nullptr, h1, NB, ND, ND);
    gemm(stream, 1, 0, h1, td2w, td2b, nullptr, h2, NB, ND, ND);
    gemm(stream, 0, 0, h2, td3w, td3b, nullptr, cp, NB, 3000, ND);
    integrate_k<<<(NB * NK + 255) / 256, 256, 0, stream>>>(cp, past, out);

    // ---- score head ----
    qscore_k<<<(NB * NK * ND + 255) / 256, 256, 0, stream>>>(q, out + 192000);
    gemm(stream, 1, 0, out, tf1w, tf1b, nullptr, tfa, NB * NK, ND, 60);
    f2bf_k<<<(1600 * 768 + 255) / 256, 256, 0, stream>>>(tfa, tfabf, 1600 * 768);
    wt_bf_k<<<dim3(24, 24), dim3(32, 8), 0, stream>>>(tf2w, tf2wT, 768, 768);
    mfma_gemm_k<0, 1, 2><<<dim3(6, 13), 256, 0, stream>>>(
        tfabf, tf2wT, tf2b, nullptr, tfbbf, nullptr, nullptr, 1600, 768, 768);
    cat_bf_k<<<(1664 * 1536 + 255) / 256, 256, 0, stream>>>(q, tfbbf, catbf);
    wt_bf_k<<<dim3(24, 48), dim3(32, 8), 0, stream>>>(sd1w, sd1wT, 1536, 768);
    mfma_gemm_k<0, 1, 2><<<dim3(6, 13), 256, 0, stream>>>(
        catbf, sd1wT, sd1b, nullptr, s1bf, nullptr, nullptr, 1600, 768, 1536);
    wt_bf_k<<<dim3(24, 24), dim3(32, 8), 0, stream>>>(sd2w, sd2wT, 768, 768);
    mfma_gemm_k<0, 1, 0><<<dim3(6, 13), 256, 0, stream>>>(
        s1bf, sd2wT, sd2b, s2, nullptr, nullptr, nullptr, 1600, 768, 768);
    score_k<<<(NB * NK + 3) / 4, 256, 0, stream>>>(s2, sd3w, sd3b, out + 1420800);
}